// Round 2
// baseline (317.585 us; speedup 1.0000x reference)
//
#include <hip/hip_runtime.h>
#include <hip/hip_bf16.h>
#include <math.h>

// ---- constants mirroring the reference ----
#define TWO_PI_D 6.283185307179586
constexpr int   NOFF  = 32768;
constexpr int   NSAMP = 128;
constexpr int   NRF   = 4;
constexpr int   NSTEP = NRF * NSAMP;   // 512
constexpr float DT    = 3.9e-05f;
constexpr float R1A   = 1.0f / 1.3f;
constexpr float R2A   = 1.0f / 0.075f;
constexpr float R1B   = 1.0f;
constexpr float R2B   = 30.0f;
constexpr float KBv   = 200.0f;
constexpr float FBv   = 0.01f;
constexpr float KAv   = FBv * KBv;     // 2.0
constexpr float DWB   = 447.0f;

struct AccPh { float a[8]; };          // [sim][rf_block] accumulated phase

// Precompute per-(sim, sample): ws = w1*sin(ph_eff), wc = w1*cos(ph_eff)
__global__ void precomp_kernel(const float* __restrict__ amps,
                               const float* __restrict__ phases,
                               AccPh acc, float2* __restrict__ wsc) {
    int tid = blockIdx.x * blockDim.x + threadIdx.x;   // 0..1023
    if (tid >= 2 * NSTEP) return;
    int sim = tid >> 9;          // 0: +200 Hz, 1: -200 Hz
    int idx = tid & (NSTEP - 1); // r*128 + i
    int r   = idx >> 7;
    float ph = -phases[idx] - acc.a[sim * 4 + r];
    float w1 = (float)(TWO_PI_D * 42.577) * amps[idx];
    wsc[tid] = make_float2(w1 * sinf(ph), w1 * cosf(ph));
}

__global__ void init_kernel(unsigned int* g) {
    if (threadIdx.x < 2) g[threadIdx.x] = 0u;
}

__global__ __launch_bounds__(256) void bmc_kernel(
        const float* __restrict__ offsets,
        const float* __restrict__ m_init,
        const float2* __restrict__ wsc,
        unsigned int* __restrict__ gmax) {
    int tid = blockIdx.x * blockDim.x + threadIdx.x;   // 0..65535
    int sim = tid >> 15;
    int o   = tid & (NOFF - 1);

    const float TP  = (float)TWO_PI_D;
    float rf  = sim ? -200.0f : 200.0f;
    float off = offsets[o];
    float dwa = TP * (off - rf);
    float dwb = TP * ((off + DWB) - rf);

    // DT-scaled matrix entries (augmented affine system, X = A*DT, b' = b*DT)
    const float dwaS = dwa * DT, dwbS = dwb * DT;
    const float caS = -(R2A + KAv) * DT;   // water transverse diag
    const float cbS = -(R1A + KAv) * DT;   // water longitudinal diag
    const float ccS = -(R2B + KBv) * DT;   // cest transverse diag
    const float cdS = -(R1B + KBv) * DT;   // cest longitudinal diag
    const float kaS = KAv * DT, kbS = KBv * DT;
    const float b2  = R1A * DT;            // b' row 2
    const float b5  = R1B * FBv * DT;      // b' row 5

    float m0 = m_init[0], m1 = m_init[1], m2 = m_init[2];
    float m3 = m_init[3], m4 = m_init[4], m5 = m_init[5];
    float lmax = 0.0f;

    const float2* __restrict__ w = wsc + sim * NSTEP;

    for (int s = 0; s < NSTEP; ++s) {
        float2 wv = w[s];
        float wsS = wv.x * DT, wcS = wv.y * DT;

        // exp(X)(m + steady offset) via order-8 Taylor on the augmented vector:
        // t1 = X*m + b'; then t_k = X*t_{k-1} / k; m += t each term.
        float t0 =  caS * m0 + dwaS * m1 - wsS * m2 + kbS * m3;
        float t1 = -dwaS * m0 + caS * m1 + wcS * m2 + kbS * m4;
        float t2 =  wsS * m0 - wcS * m1 + cbS * m2 + kbS * m5 + b2;
        float t3 =  kaS * m0 + ccS * m3 + dwbS * m4 - wsS * m5;
        float t4 =  kaS * m1 - dwbS * m3 + ccS * m4 + wcS * m5;
        float t5 =  kaS * m2 + wsS * m3 - wcS * m4 + cdS * m5 + b5;
        m0 += t0; m1 += t1; m2 += t2; m3 += t3; m4 += t4; m5 += t5;

#pragma unroll
        for (int k = 2; k <= 8; ++k) {
            const float rk = 1.0f / (float)k;
            float s0 = ( caS * t0 + dwaS * t1 - wsS * t2 + kbS * t3) * rk;
            float s1 = (-dwaS * t0 + caS * t1 + wcS * t2 + kbS * t4) * rk;
            float s2 = ( wsS * t0 - wcS * t1 + cbS * t2 + kbS * t5) * rk;
            float s3 = ( kaS * t0 + ccS * t3 + dwbS * t4 - wsS * t5) * rk;
            float s4 = ( kaS * t1 - dwbS * t3 + ccS * t4 + wcS * t5) * rk;
            float s5 = ( kaS * t2 + wsS * t3 - wcS * t4 + cdS * t5) * rk;
            t0 = s0; t1 = s1; t2 = s2; t3 = s3; t4 = s4; t5 = s5;
            m0 += t0; m1 += t1; m2 += t2; m3 += t3; m4 += t4; m5 += t5;
        }

        float tr2 = m0 * m0 + m1 * m1;   // sqrt deferred (monotone)
        lmax = fmaxf(lmax, tr2);
    }

    // wave-64 max reduce, then one atomic per wave (sim uniform per wave)
    for (int d = 32; d >= 1; d >>= 1)
        lmax = fmaxf(lmax, __shfl_xor(lmax, d, 64));
    if ((threadIdx.x & 63) == 0)
        atomicMax(gmax + sim, __float_as_uint(lmax));   // all values >= 0
}

__global__ void finalize_kernel(const unsigned int* __restrict__ gmax,
                                float* __restrict__ out) {
    int i = threadIdx.x;
    if (i < 2) out[i] = sqrtf(__uint_as_float(gmax[i]));   // float32 output!
}

extern "C" void kernel_launch(void* const* d_in, const int* in_sizes, int n_in,
                              void* d_out, int out_size, void* d_ws, size_t ws_size,
                              hipStream_t stream) {
    const float* amps    = (const float*)d_in[0];   // (4,128)
    const float* phases  = (const float*)d_in[1];   // (4,128)
    const float* offsets = (const float*)d_in[2];   // (32768,)
    const float* m_init  = (const float*)d_in[3];   // (6,)
    float* out           = (float*)d_out;           // (2,) float32

    unsigned int* gmax = (unsigned int*)d_ws;                 // 2 slots
    float2* wsc = (float2*)((char*)d_ws + 256);               // 2*512 float2

    // Python-semantics accumulated phase per (sim, rf block), computed in f64
    AccPh acc;
    for (int s = 0; s < 2; ++s) {
        double rfo  = s ? -200.0 : 200.0;
        double accp = 0.0;
        for (int r = 0; r < NRF; ++r) {
            acc.a[s * 4 + r] = (float)accp;
            double pd = fmod(3.9e-05 * 128.0 * 360.0 * rfo, 360.0);
            if (pd < 0.0) pd += 360.0;      // Python % semantics
            accp += pd / 180.0 * M_PI;
        }
    }

    init_kernel<<<1, 64, 0, stream>>>(gmax);
    precomp_kernel<<<4, 256, 0, stream>>>(amps, phases, acc, wsc);
    bmc_kernel<<<(2 * NOFF) / 256, 256, 0, stream>>>(offsets, m_init, wsc, gmax);
    finalize_kernel<<<1, 64, 0, stream>>>(gmax, out);
}

// Round 3
// 179.403 us; speedup vs baseline: 1.7702x; 1.7702x over previous
//
#include <hip/hip_runtime.h>
#include <hip/hip_bf16.h>
#include <math.h>

// ---- constants mirroring the reference ----
#define TWO_PI_D 6.283185307179586
constexpr int   NOFF  = 32768;
constexpr int   NSAMP = 128;
constexpr int   NRF   = 4;
constexpr int   NSTEP = NRF * NSAMP;   // 512
constexpr float DT    = 3.9e-05f;
constexpr float R1A   = 1.0f / 1.3f;
constexpr float R2A   = 1.0f / 0.075f;
constexpr float R1B   = 1.0f;
constexpr float R2B   = 30.0f;
constexpr float KBv   = 200.0f;
constexpr float FBv   = 0.01f;
constexpr float KAv   = FBv * KBv;     // 2.0
constexpr float DWB   = 447.0f;

struct AccPh { float a[8]; };          // [sim][rf_block] accumulated phase

// Precompute per-(sim, sample): ws = w1*sin(ph_eff)*DT, wc = w1*cos(ph_eff)*DT
// (DT folded in so the hot loop uses the values directly)
__global__ void precomp_kernel(const float* __restrict__ amps,
                               const float* __restrict__ phases,
                               AccPh acc, float2* __restrict__ wsc) {
    int tid = blockIdx.x * blockDim.x + threadIdx.x;   // 0..1023
    if (tid >= 2 * NSTEP) return;
    int sim = tid >> 9;          // 0: +200 Hz, 1: -200 Hz
    int idx = tid & (NSTEP - 1); // r*128 + i
    int r   = idx >> 7;
    float ph = -phases[idx] - acc.a[sim * 4 + r];
    float w1 = (float)(TWO_PI_D * 42.577) * amps[idx];
    wsc[tid] = make_float2(w1 * sinf(ph) * DT, w1 * cosf(ph) * DT);
}

__global__ void init_kernel(unsigned int* g) {
    if (threadIdx.x < 2) g[threadIdx.x] = 0u;
}

__global__ __launch_bounds__(256) void bmc_kernel(
        const float* __restrict__ offsets,
        const float* __restrict__ m_init,
        const float2* __restrict__ wsc,
        unsigned int* __restrict__ gmax) {
    int tid = blockIdx.x * blockDim.x + threadIdx.x;   // 0..65535
    int sim = tid >> 15;
    int o   = tid & (NOFF - 1);

    const float TP  = (float)TWO_PI_D;
    float rf  = sim ? -200.0f : 200.0f;
    float off = offsets[o];
    float dwa = TP * (off - rf);
    float dwb = TP * ((off + DWB) - rf);

    // DT-scaled matrix entries (augmented affine system, X = A*DT, b' = b*DT)
    const float dwaS = dwa * DT, dwbS = dwb * DT;
    const float caS = -(R2A + KAv) * DT;   // water transverse diag
    const float cbS = -(R1A + KAv) * DT;   // water longitudinal diag
    const float ccS = -(R2B + KBv) * DT;   // cest transverse diag
    const float cdS = -(R1B + KBv) * DT;   // cest longitudinal diag
    const float kaS = KAv * DT, kbS = KBv * DT;
    const float b2  = R1A * DT;            // b' row 2
    const float b5  = R1B * FBv * DT;      // b' row 5

    float m0 = m_init[0], m1 = m_init[1], m2 = m_init[2];
    float m3 = m_init[3], m4 = m_init[4], m5 = m_init[5];
    float lmax = 0.0f;

    // One step: order-7 Taylor of exp(X) applied to the augmented vector,
    // with UNNORMALIZED Krylov terms u_k = X^k u_0 and coefficient-FMA
    // accumulation m += u_k / k!  (saves 6 ops/term vs normalize-then-add).
#define BMC_STEP(wsS, wcS)                                                     \
    {                                                                          \
        float u0 = fmaf(caS, m0, fmaf(dwaS, m1, fmaf(-(wsS), m2, kbS * m3)));  \
        float u1 = fmaf(-dwaS, m0, fmaf(caS, m1, fmaf((wcS), m2, kbS * m4)));  \
        float u2 = fmaf((wsS), m0, fmaf(-(wcS), m1, fmaf(cbS, m2, fmaf(kbS, m5, b2)))); \
        float u3 = fmaf(kaS, m0, fmaf(ccS, m3, fmaf(dwbS, m4, -(wsS) * m5)));  \
        float u4 = fmaf(kaS, m1, fmaf(-dwbS, m3, fmaf(ccS, m4, (wcS) * m5)));  \
        float u5 = fmaf(kaS, m2, fmaf((wsS), m3, fmaf(-(wcS), m4, fmaf(cdS, m5, b5)))); \
        m0 += u0; m1 += u1; m2 += u2; m3 += u3; m4 += u4; m5 += u5;            \
        _Pragma("unroll")                                                      \
        for (int k = 2; k <= 7; ++k) {                                         \
            const float ck = (k == 2) ? 0.5f : (k == 3) ? (1.0f / 6.0f)        \
                           : (k == 4) ? (1.0f / 24.0f) : (k == 5) ? (1.0f / 120.0f) \
                           : (k == 6) ? (1.0f / 720.0f) : (1.0f / 5040.0f);    \
            float v0 = fmaf(caS, u0, fmaf(dwaS, u1, fmaf(-(wsS), u2, kbS * u3))); \
            float v1 = fmaf(-dwaS, u0, fmaf(caS, u1, fmaf((wcS), u2, kbS * u4))); \
            float v2 = fmaf((wsS), u0, fmaf(-(wcS), u1, fmaf(cbS, u2, kbS * u5))); \
            float v3 = fmaf(kaS, u0, fmaf(ccS, u3, fmaf(dwbS, u4, -(wsS) * u5))); \
            float v4 = fmaf(kaS, u1, fmaf(-dwbS, u3, fmaf(ccS, u4, (wcS) * u5))); \
            float v5 = fmaf(kaS, u2, fmaf((wsS), u3, fmaf(-(wcS), u4, cdS * u5))); \
            u0 = v0; u1 = v1; u2 = v2; u3 = v3; u4 = v4; u5 = v5;              \
            m0 = fmaf(u0, ck, m0); m1 = fmaf(u1, ck, m1);                      \
            m2 = fmaf(u2, ck, m2); m3 = fmaf(u3, ck, m3);                      \
            m4 = fmaf(u4, ck, m4); m5 = fmaf(u5, ck, m5);                      \
        }                                                                      \
        float tr2 = fmaf(m0, m0, m1 * m1);                                     \
        lmax = fmaxf(lmax, tr2);                                               \
    }

    // 4 steps per iteration; two float4 loads prefetched one iteration ahead
    const float4* __restrict__ w4 = (const float4*)(wsc + sim * NSTEP); // 256 x float4
    float4 wA = w4[0], wB = w4[1];
    for (int j = 0; j < NSTEP / 4; ++j) {
        int jn = (j + 1) & (NSTEP / 4 - 1);          // wraps to 0 on last iter
        float4 nA = w4[2 * jn];
        float4 nB = w4[2 * jn + 1];
        BMC_STEP(wA.x, wA.y)
        BMC_STEP(wA.z, wA.w)
        BMC_STEP(wB.x, wB.y)
        BMC_STEP(wB.z, wB.w)
        wA = nA; wB = nB;
    }
#undef BMC_STEP

    // wave-64 max reduce, then one atomic per wave (sim uniform per wave)
    for (int d = 32; d >= 1; d >>= 1)
        lmax = fmaxf(lmax, __shfl_xor(lmax, d, 64));
    if ((threadIdx.x & 63) == 0)
        atomicMax(gmax + sim, __float_as_uint(lmax));   // all values >= 0

    (void)NSAMP;
}

__global__ void finalize_kernel(const unsigned int* __restrict__ gmax,
                                float* __restrict__ out) {
    int i = threadIdx.x;
    if (i < 2) out[i] = sqrtf(__uint_as_float(gmax[i]));   // float32 output
}

extern "C" void kernel_launch(void* const* d_in, const int* in_sizes, int n_in,
                              void* d_out, int out_size, void* d_ws, size_t ws_size,
                              hipStream_t stream) {
    const float* amps    = (const float*)d_in[0];   // (4,128)
    const float* phases  = (const float*)d_in[1];   // (4,128)
    const float* offsets = (const float*)d_in[2];   // (32768,)
    const float* m_init  = (const float*)d_in[3];   // (6,)
    float* out           = (float*)d_out;           // (2,) float32

    unsigned int* gmax = (unsigned int*)d_ws;                 // 2 slots
    float2* wsc = (float2*)((char*)d_ws + 256);               // 2*512 float2

    // Python-semantics accumulated phase per (sim, rf block), computed in f64
    AccPh acc;
    for (int s = 0; s < 2; ++s) {
        double rfo  = s ? -200.0 : 200.0;
        double accp = 0.0;
        for (int r = 0; r < NRF; ++r) {
            acc.a[s * 4 + r] = (float)accp;
            double pd = fmod(3.9e-05 * 128.0 * 360.0 * rfo, 360.0);
            if (pd < 0.0) pd += 360.0;      // Python % semantics
            accp += pd / 180.0 * M_PI;
        }
    }

    init_kernel<<<1, 64, 0, stream>>>(gmax);
    precomp_kernel<<<4, 256, 0, stream>>>(amps, phases, acc, wsc);
    bmc_kernel<<<(2 * NOFF) / 256, 256, 0, stream>>>(offsets, m_init, wsc, gmax);
    finalize_kernel<<<1, 64, 0, stream>>>(gmax, out);
}

// Round 4
// 131.311 us; speedup vs baseline: 2.4186x; 1.3662x over previous
//
#include <hip/hip_runtime.h>
#include <hip/hip_bf16.h>
#include <math.h>

// ---- constants mirroring the reference ----
#define TWO_PI_D 6.283185307179586
constexpr int   NOFF  = 32768;
constexpr int   NSAMP = 128;
constexpr int   NRF   = 4;
constexpr int   NSTEP = NRF * NSAMP;   // 512
constexpr float DT    = 3.9e-05f;
constexpr float R1A   = 1.0f / 1.3f;
constexpr float R2A   = 1.0f / 0.075f;
constexpr float R1B   = 1.0f;
constexpr float R2B   = 30.0f;
constexpr float KBv   = 200.0f;
constexpr float FBv   = 0.01f;
constexpr float KAv   = FBv * KBv;     // 2.0
constexpr float DWB   = 447.0f;

struct AccPh { float a[8]; };          // [sim][rf_block] accumulated phase

// Precompute per-(sim, sample): ws = w1*sin(ph_eff)*DT, wc = w1*cos(ph_eff)*DT
__global__ void precomp_kernel(const float* __restrict__ amps,
                               const float* __restrict__ phases,
                               AccPh acc, float2* __restrict__ wsc) {
    int tid = blockIdx.x * blockDim.x + threadIdx.x;   // 0..1023
    if (tid >= 2 * NSTEP) return;
    int sim = tid >> 9;          // 0: +200 Hz, 1: -200 Hz
    int idx = tid & (NSTEP - 1); // r*128 + i
    int r   = idx >> 7;
    float ph = -phases[idx] - acc.a[sim * 4 + r];
    float w1 = (float)(TWO_PI_D * 42.577) * amps[idx];
    wsc[tid] = make_float2(w1 * sinf(ph) * DT, w1 * cosf(ph) * DT);
}

__global__ void init_kernel(unsigned int* g) {
    if (threadIdx.x < 2) g[threadIdx.x] = 0u;
}

__global__ __launch_bounds__(256) void bmc_kernel(
        const float* __restrict__ offsets,
        const float* __restrict__ m_init,
        const float2* __restrict__ wsc,
        unsigned int* __restrict__ gmax) {
    int tid = blockIdx.x * blockDim.x + threadIdx.x;   // 0..65535
    int sim = tid >> 15;
    int o   = tid & (NOFF - 1);

    const float TP  = (float)TWO_PI_D;
    float rf  = sim ? -200.0f : 200.0f;
    float off = offsets[o];
    float dwa = TP * (off - rf);
    float dwb = TP * ((off + DWB) - rf);

    // DT-scaled matrix entries (augmented affine system, X = A*DT, b' = b*DT)
    const float dwaS = dwa * DT, dwbS = dwb * DT;
    const float caS = -(R2A + KAv) * DT;   // water transverse diag
    const float cbS = -(R1A + KAv) * DT;   // water longitudinal diag
    const float ccS = -(R2B + KBv) * DT;   // cest transverse diag
    const float cdS = -(R1B + KBv) * DT;   // cest longitudinal diag
    const float kaS = KAv * DT, kbS = KBv * DT;
    const float b2  = R1A * DT;            // b' row 2
    const float b5  = R1B * FBv * DT;      // b' row 5

    float m0 = m_init[0], m1 = m_init[1], m2 = m_init[2];
    float m3 = m_init[3], m4 = m_init[4], m5 = m_init[5];
    float lmax = 0.0f;

    // Degree-5 polynomial approximation of exp(X) on the spectral strip
    // |Im z| <= 0.53, Re z in [-0.013, 0]: Chebyshev-truncated coefficients
    // (even part ~ cos to 2e-6, odd part ~ sin to 4e-8 on [-0.53,0.53]),
    // a0 constrained to exactly 1. m' = m + sum_k Ak * u_k, u_k = X u_{k-1},
    // u_1 = X m + b.  512-step worst-case accumulated error ~1e-3 << 1.8e-2.
    const float A1 = 1.0000020f;
    const float CK[4] = { 0.4999373f, 0.1666530f, 0.0410804f, 0.0082358f };

#define BMC_STEP(wsS, wcS)                                                     \
    {                                                                          \
        float u0 = fmaf(caS, m0, fmaf(dwaS, m1, fmaf(-(wsS), m2, kbS * m3)));  \
        float u1 = fmaf(-dwaS, m0, fmaf(caS, m1, fmaf((wcS), m2, kbS * m4)));  \
        float u2 = fmaf((wsS), m0, fmaf(-(wcS), m1, fmaf(cbS, m2, fmaf(kbS, m5, b2)))); \
        float u3 = fmaf(kaS, m0, fmaf(ccS, m3, fmaf(dwbS, m4, -(wsS) * m5)));  \
        float u4 = fmaf(kaS, m1, fmaf(-dwbS, m3, fmaf(ccS, m4, (wcS) * m5)));  \
        float u5 = fmaf(kaS, m2, fmaf((wsS), m3, fmaf(-(wcS), m4, fmaf(cdS, m5, b5)))); \
        m0 = fmaf(A1, u0, m0); m1 = fmaf(A1, u1, m1); m2 = fmaf(A1, u2, m2);   \
        m3 = fmaf(A1, u3, m3); m4 = fmaf(A1, u4, m4); m5 = fmaf(A1, u5, m5);   \
        _Pragma("unroll")                                                      \
        for (int k = 0; k < 4; ++k) {                                          \
            const float ck = CK[k];                                            \
            float v0 = fmaf(caS, u0, fmaf(dwaS, u1, fmaf(-(wsS), u2, kbS * u3))); \
            float v1 = fmaf(-dwaS, u0, fmaf(caS, u1, fmaf((wcS), u2, kbS * u4))); \
            float v2 = fmaf((wsS), u0, fmaf(-(wcS), u1, fmaf(cbS, u2, kbS * u5))); \
            float v3 = fmaf(kaS, u0, fmaf(ccS, u3, fmaf(dwbS, u4, -(wsS) * u5))); \
            float v4 = fmaf(kaS, u1, fmaf(-dwbS, u3, fmaf(ccS, u4, (wcS) * u5))); \
            float v5 = fmaf(kaS, u2, fmaf((wsS), u3, fmaf(-(wcS), u4, cdS * u5))); \
            u0 = v0; u1 = v1; u2 = v2; u3 = v3; u4 = v4; u5 = v5;              \
            m0 = fmaf(ck, u0, m0); m1 = fmaf(ck, u1, m1);                      \
            m2 = fmaf(ck, u2, m2); m3 = fmaf(ck, u3, m3);                      \
            m4 = fmaf(ck, u4, m4); m5 = fmaf(ck, u5, m5);                      \
        }                                                                      \
        lmax = fmaxf(lmax, fmaf(m0, m0, m1 * m1));                             \
    }

    // 4 steps per iteration; two float4 loads prefetched one iteration ahead
    const float4* __restrict__ w4 = (const float4*)(wsc + sim * NSTEP); // 256 x float4
    float4 wA = w4[0], wB = w4[1];
    for (int j = 0; j < NSTEP / 4; ++j) {
        int jn = (j + 1) & (NSTEP / 4 - 1);          // wraps to 0 on last iter
        float4 nA = w4[2 * jn];
        float4 nB = w4[2 * jn + 1];
        BMC_STEP(wA.x, wA.y)
        BMC_STEP(wA.z, wA.w)
        BMC_STEP(wB.x, wB.y)
        BMC_STEP(wB.z, wB.w)
        wA = nA; wB = nB;
    }
#undef BMC_STEP

    // wave-64 max reduce, then one atomic per wave (sim uniform per wave)
    for (int d = 32; d >= 1; d >>= 1)
        lmax = fmaxf(lmax, __shfl_xor(lmax, d, 64));
    if ((threadIdx.x & 63) == 0)
        atomicMax(gmax + sim, __float_as_uint(lmax));   // all values >= 0

    (void)NSAMP;
}

__global__ void finalize_kernel(const unsigned int* __restrict__ gmax,
                                float* __restrict__ out) {
    int i = threadIdx.x;
    if (i < 2) out[i] = sqrtf(__uint_as_float(gmax[i]));   // float32 output
}

extern "C" void kernel_launch(void* const* d_in, const int* in_sizes, int n_in,
                              void* d_out, int out_size, void* d_ws, size_t ws_size,
                              hipStream_t stream) {
    const float* amps    = (const float*)d_in[0];   // (4,128)
    const float* phases  = (const float*)d_in[1];   // (4,128)
    const float* offsets = (const float*)d_in[2];   // (32768,)
    const float* m_init  = (const float*)d_in[3];   // (6,)
    float* out           = (float*)d_out;           // (2,) float32

    unsigned int* gmax = (unsigned int*)d_ws;                 // 2 slots
    float2* wsc = (float2*)((char*)d_ws + 256);               // 2*512 float2

    // Python-semantics accumulated phase per (sim, rf block), computed in f64
    AccPh acc;
    for (int s = 0; s < 2; ++s) {
        double rfo  = s ? -200.0 : 200.0;
        double accp = 0.0;
        for (int r = 0; r < NRF; ++r) {
            acc.a[s * 4 + r] = (float)accp;
            double pd = fmod(3.9e-05 * 128.0 * 360.0 * rfo, 360.0);
            if (pd < 0.0) pd += 360.0;      // Python % semantics
            accp += pd / 180.0 * M_PI;
        }
    }

    init_kernel<<<1, 64, 0, stream>>>(gmax);
    precomp_kernel<<<4, 256, 0, stream>>>(amps, phases, acc, wsc);
    bmc_kernel<<<(2 * NOFF) / 256, 256, 0, stream>>>(offsets, m_init, wsc, gmax);
    finalize_kernel<<<1, 64, 0, stream>>>(gmax, out);
}

// Round 5
// 119.688 us; speedup vs baseline: 2.6534x; 1.0971x over previous
//
#include <hip/hip_runtime.h>
#include <hip/hip_bf16.h>
#include <math.h>

// ---- constants mirroring the reference ----
#define TWO_PI_D 6.283185307179586
constexpr int   NOFF  = 32768;
constexpr int   NSAMP = 128;
constexpr int   NRF   = 4;
constexpr int   NSTEP = NRF * NSAMP;   // 512
constexpr float DT    = 3.9e-05f;
constexpr float R1A   = 1.0f / 1.3f;
constexpr float R2A   = 1.0f / 0.075f;
constexpr float R1B   = 1.0f;
constexpr float R2B   = 30.0f;
constexpr float KBv   = 200.0f;
constexpr float FBv   = 0.01f;
constexpr float KAv   = FBv * KBv;     // 2.0
constexpr float DWB   = 447.0f;

struct AccPh { float a[8]; };          // [sim][rf_block] accumulated phase

// Precompute per-(sim, sample): ws = w1*sin(ph_eff)*DT, wc = w1*cos(ph_eff)*DT
__global__ void precomp_kernel(const float* __restrict__ amps,
                               const float* __restrict__ phases,
                               AccPh acc, float2* __restrict__ wsc) {
    int tid = blockIdx.x * blockDim.x + threadIdx.x;   // 0..1023
    if (tid >= 2 * NSTEP) return;
    int sim = tid >> 9;          // 0: +200 Hz, 1: -200 Hz
    int idx = tid & (NSTEP - 1); // r*128 + i
    int r   = idx >> 7;
    float ph = -phases[idx] - acc.a[sim * 4 + r];
    float w1 = (float)(TWO_PI_D * 42.577) * amps[idx];
    wsc[tid] = make_float2(w1 * sinf(ph) * DT, w1 * cosf(ph) * DT);
}

__global__ void init_kernel(unsigned int* g) {
    if (threadIdx.x < 2) g[threadIdx.x] = 0u;
}

__global__ __launch_bounds__(256) void bmc_kernel(
        const float* __restrict__ offsets,
        const float* __restrict__ m_init,
        const float2* __restrict__ wsc,
        unsigned int* __restrict__ gmax) {
    int tid = blockIdx.x * blockDim.x + threadIdx.x;   // 0..65535
    int sim = tid >> 15;
    int o   = tid & (NOFF - 1);

    const float TP  = (float)TWO_PI_D;
    float rf  = sim ? -200.0f : 200.0f;
    float off = offsets[o];
    float dwa = TP * (off - rf);
    float dwb = TP * ((off + DWB) - rf);

    // DT-scaled matrix entries (augmented affine system, X = A*DT, b' = b*DT)
    const float dwaS = dwa * DT, dwbS = dwb * DT;
    const float caS = -(R2A + KAv) * DT;   // water transverse diag
    const float cbS = -(R1A + KAv) * DT;   // water longitudinal diag
    const float ccS = -(R2B + KBv) * DT;   // cest transverse diag
    const float cdS = -(R1B + KBv) * DT;   // cest longitudinal diag
    const float kaS = KAv * DT, kbS = KBv * DT;
    const float b2  = R1A * DT;            // b' row 2
    const float b5  = R1B * FBv * DT;      // b' row 5

    float m0 = m_init[0], m1 = m_init[1], m2 = m_init[2];
    float m3 = m_init[3], m4 = m_init[4], m5 = m_init[5];
    float lmax = 0.0f;

    // Degree-4 TAYLOR of exp(X) on the augmented affine system.
    // Rationale: the global max is carried by near-resonance threads where
    // theta = ||X|| <= ~0.15; Taylor-4 amplitude defect there is
    // |p(i·th)|-1 ~ -th^6/144 -> 512-step accumulation <= ~1e-4.
    // Far-off-resonance threads (theta up to 0.53) have larger error but
    // |Mxy| ~ w1/dw << max, so they never contend for the output max.
    const float CK[3] = { 0.5f, 1.0f / 6.0f, 1.0f / 24.0f };

#define BMC_STEP(wsS, wcS)                                                     \
    {                                                                          \
        float u0 = fmaf(caS, m0, fmaf(dwaS, m1, fmaf(-(wsS), m2, kbS * m3)));  \
        float u1 = fmaf(-dwaS, m0, fmaf(caS, m1, fmaf((wcS), m2, kbS * m4)));  \
        float u2 = fmaf((wsS), m0, fmaf(-(wcS), m1, fmaf(cbS, m2, fmaf(kbS, m5, b2)))); \
        float u3 = fmaf(kaS, m0, fmaf(ccS, m3, fmaf(dwbS, m4, -(wsS) * m5)));  \
        float u4 = fmaf(kaS, m1, fmaf(-dwbS, m3, fmaf(ccS, m4, (wcS) * m5)));  \
        float u5 = fmaf(kaS, m2, fmaf((wsS), m3, fmaf(-(wcS), m4, fmaf(cdS, m5, b5)))); \
        m0 += u0; m1 += u1; m2 += u2; m3 += u3; m4 += u4; m5 += u5;            \
        _Pragma("unroll")                                                      \
        for (int k = 0; k < 3; ++k) {                                          \
            const float ck = CK[k];                                            \
            float v0 = fmaf(caS, u0, fmaf(dwaS, u1, fmaf(-(wsS), u2, kbS * u3))); \
            float v1 = fmaf(-dwaS, u0, fmaf(caS, u1, fmaf((wcS), u2, kbS * u4))); \
            float v2 = fmaf((wsS), u0, fmaf(-(wcS), u1, fmaf(cbS, u2, kbS * u5))); \
            float v3 = fmaf(kaS, u0, fmaf(ccS, u3, fmaf(dwbS, u4, -(wsS) * u5))); \
            float v4 = fmaf(kaS, u1, fmaf(-dwbS, u3, fmaf(ccS, u4, (wcS) * u5))); \
            float v5 = fmaf(kaS, u2, fmaf((wsS), u3, fmaf(-(wcS), u4, cdS * u5))); \
            u0 = v0; u1 = v1; u2 = v2; u3 = v3; u4 = v4; u5 = v5;              \
            m0 = fmaf(ck, u0, m0); m1 = fmaf(ck, u1, m1);                      \
            m2 = fmaf(ck, u2, m2); m3 = fmaf(ck, u3, m3);                      \
            m4 = fmaf(ck, u4, m4); m5 = fmaf(ck, u5, m5);                      \
        }                                                                      \
        lmax = fmaxf(lmax, fmaf(m0, m0, m1 * m1));                             \
    }

    // 8 steps per iteration; four float4 loads prefetched one iteration ahead
    const float4* __restrict__ w4 = (const float4*)(wsc + sim * NSTEP); // 256 x float4
    float4 p0 = w4[0], p1 = w4[1], p2 = w4[2], p3 = w4[3];
    for (int j = 0; j < NSTEP / 8; ++j) {
        int jn = (j + 1) & (NSTEP / 8 - 1);          // wraps to 0 on last iter
        float4 n0 = w4[4 * jn];
        float4 n1 = w4[4 * jn + 1];
        float4 n2 = w4[4 * jn + 2];
        float4 n3 = w4[4 * jn + 3];
        BMC_STEP(p0.x, p0.y)
        BMC_STEP(p0.z, p0.w)
        BMC_STEP(p1.x, p1.y)
        BMC_STEP(p1.z, p1.w)
        BMC_STEP(p2.x, p2.y)
        BMC_STEP(p2.z, p2.w)
        BMC_STEP(p3.x, p3.y)
        BMC_STEP(p3.z, p3.w)
        p0 = n0; p1 = n1; p2 = n2; p3 = n3;
    }
#undef BMC_STEP

    // wave-64 max reduce, then one atomic per wave (sim uniform per wave)
    for (int d = 32; d >= 1; d >>= 1)
        lmax = fmaxf(lmax, __shfl_xor(lmax, d, 64));
    if ((threadIdx.x & 63) == 0)
        atomicMax(gmax + sim, __float_as_uint(lmax));   // all values >= 0

    (void)NSAMP;
}

__global__ void finalize_kernel(const unsigned int* __restrict__ gmax,
                                float* __restrict__ out) {
    int i = threadIdx.x;
    if (i < 2) out[i] = sqrtf(__uint_as_float(gmax[i]));   // float32 output
}

extern "C" void kernel_launch(void* const* d_in, const int* in_sizes, int n_in,
                              void* d_out, int out_size, void* d_ws, size_t ws_size,
                              hipStream_t stream) {
    const float* amps    = (const float*)d_in[0];   // (4,128)
    const float* phases  = (const float*)d_in[1];   // (4,128)
    const float* offsets = (const float*)d_in[2];   // (32768,)
    const float* m_init  = (const float*)d_in[3];   // (6,)
    float* out           = (float*)d_out;           // (2,) float32

    unsigned int* gmax = (unsigned int*)d_ws;                 // 2 slots
    float2* wsc = (float2*)((char*)d_ws + 256);               // 2*512 float2

    // Python-semantics accumulated phase per (sim, rf block), computed in f64
    AccPh acc;
    for (int s = 0; s < 2; ++s) {
        double rfo  = s ? -200.0 : 200.0;
        double accp = 0.0;
        for (int r = 0; r < NRF; ++r) {
            acc.a[s * 4 + r] = (float)accp;
            double pd = fmod(3.9e-05 * 128.0 * 360.0 * rfo, 360.0);
            if (pd < 0.0) pd += 360.0;      // Python % semantics
            accp += pd / 180.0 * M_PI;
        }
    }

    init_kernel<<<1, 64, 0, stream>>>(gmax);
    precomp_kernel<<<4, 256, 0, stream>>>(amps, phases, acc, wsc);
    bmc_kernel<<<(2 * NOFF) / 256, 256, 0, stream>>>(offsets, m_init, wsc, gmax);
    finalize_kernel<<<1, 64, 0, stream>>>(gmax, out);
}

// Round 6
// 99.450 us; speedup vs baseline: 3.1934x; 1.2035x over previous
//
#include <hip/hip_runtime.h>
#include <hip/hip_bf16.h>
#include <math.h>

// ---- constants mirroring the reference ----
#define TWO_PI_D 6.283185307179586
constexpr int   NOFF  = 32768;
constexpr int   NSAMP = 128;
constexpr int   NRF   = 4;
constexpr int   NSTEP = NRF * NSAMP;   // 512
constexpr float DT    = 3.9e-05f;
constexpr float R1A   = 1.0f / 1.3f;
constexpr float R2A   = 1.0f / 0.075f;
constexpr float R1B   = 1.0f;
constexpr float R2B   = 30.0f;
constexpr float KBv   = 200.0f;
constexpr float FBv   = 0.01f;
constexpr float KAv   = FBv * KBv;     // 2.0
constexpr float DWB   = 447.0f;

typedef float f32x2 __attribute__((ext_vector_type(2)));

// ---- VOP3P packed-f32 helpers (64-bit VGPR pairs, 2 f32 per lane) ----
// op_sel[k]    : which half of src k feeds the LOW  result (0=lo,1=hi)
// op_sel_hi[k] : which half of src k feeds the HIGH result (default 1)
// neg_lo/neg_hi: negate src k's contribution per result half
#define PK_FMA_ACC(acc, a, b) \
    asm("v_pk_fma_f32 %0, %1, %2, %0" : "+v"(acc) : "v"(a), "v"(b))
#define PK_FMA_ACC_NEG0(acc, a, b) \
    asm("v_pk_fma_f32 %0, %1, %2, %0 neg_lo:[1,0,0] neg_hi:[1,0,0]" : "+v"(acc) : "v"(a), "v"(b))
// src0 = (ws,wc) table pair; dup LOW half (ws) into both mul lanes
#define PK_FMA_ACC_WSLO(acc, w, b) \
    asm("v_pk_fma_f32 %0, %1, %2, %0 op_sel:[0,0,0] op_sel_hi:[0,1,1]" : "+v"(acc) : "v"(w), "v"(b))
#define PK_FMA_ACC_WSLO_NEG(acc, w, b) \
    asm("v_pk_fma_f32 %0, %1, %2, %0 op_sel:[0,0,0] op_sel_hi:[0,1,1] neg_lo:[1,0,0] neg_hi:[1,0,0]" : "+v"(acc) : "v"(w), "v"(b))
// dup HIGH half (wc) into both mul lanes
#define PK_FMA_ACC_WCHI(acc, w, b) \
    asm("v_pk_fma_f32 %0, %1, %2, %0 op_sel:[1,0,0] op_sel_hi:[1,1,1]" : "+v"(acc) : "v"(w), "v"(b))
#define PK_FMA_ACC_WCHI_NEG(acc, w, b) \
    asm("v_pk_fma_f32 %0, %1, %2, %0 op_sel:[1,0,0] op_sel_hi:[1,1,1] neg_lo:[1,0,0] neg_hi:[1,0,0]" : "+v"(acc) : "v"(w), "v"(b))
// d = a * swap(s)   (exchange coupling: lo = a.lo*s.hi, hi = a.hi*s.lo)
#define PK_MUL_SWAP1(d, a, s) \
    asm("v_pk_mul_f32 %0, %1, %2 op_sel:[0,1] op_sel_hi:[1,0]" : "=v"(d) : "v"(a), "v"(s))
// d = a * swap(s) + c   (first-term exchange + b-vector constant)
#define PK_FMA_SWAP1(d, a, s, c) \
    asm("v_pk_fma_f32 %0, %1, %2, %3 op_sel:[0,1,0] op_sel_hi:[1,0,1]" : "=v"(d) : "v"(a), "v"(s), "v"(c))
#define PK_ADD_ACC(acc, u) \
    asm("v_pk_add_f32 %0, %1, %0" : "+v"(acc) : "v"(u))

struct AccPh { float a[8]; };          // [sim][rf_block] accumulated phase

// Precompute per-(sim, sample): ws = w1*sin(ph_eff)*DT, wc = w1*cos(ph_eff)*DT
__global__ void precomp_kernel(const float* __restrict__ amps,
                               const float* __restrict__ phases,
                               AccPh acc, float2* __restrict__ wsc) {
    int tid = blockIdx.x * blockDim.x + threadIdx.x;   // 0..1023
    if (tid >= 2 * NSTEP) return;
    int sim = tid >> 9;          // 0: +200 Hz, 1: -200 Hz
    int idx = tid & (NSTEP - 1); // r*128 + i
    int r   = idx >> 7;
    float ph = -phases[idx] - acc.a[sim * 4 + r];
    float w1 = (float)(TWO_PI_D * 42.577) * amps[idx];
    wsc[tid] = make_float2(w1 * sinf(ph) * DT, w1 * cosf(ph) * DT);
}

__global__ void init_kernel(unsigned int* g) {
    if (threadIdx.x < 2) g[threadIdx.x] = 0u;
}

__global__ __launch_bounds__(256) void bmc_kernel(
        const float* __restrict__ offsets,
        const float* __restrict__ m_init,
        const float2* __restrict__ wsc,
        unsigned int* __restrict__ gmax) {
    int tid = blockIdx.x * blockDim.x + threadIdx.x;   // 0..65535
    int sim = tid >> 15;
    int o   = tid & (NOFF - 1);

    const float TP  = (float)TWO_PI_D;
    float rf  = sim ? -200.0f : 200.0f;
    float off = offsets[o];
    float dwa = TP * (off - rf);
    float dwb = TP * ((off + DWB) - rf);

    // Pair layout: A=(m0,m3), B=(m1,m4), C=(m2,m5) — the two pools' matching
    // components share a 64-bit VGPR pair. Rotation terms are lane-aligned,
    // exchange (ka/kb) terms are within-pair swaps (op_sel), ws/wc broadcast
    // comes from op_sel dup on the (ws,wc) table pair. Constant pairs:
    const f32x2 CA2 = { -(R2A + KAv) * DT, -(R2B + KBv) * DT };  // transverse diags
    const f32x2 CB2 = { -(R1A + KAv) * DT, -(R1B + KBv) * DT };  // longitudinal diags
    const f32x2 DW2 = { dwa * DT, dwb * DT };
    const f32x2 KX2 = { KBv * DT, KAv * DT };                    // (kb, ka)
    const f32x2 BP2 = { R1A * DT, R1B * FBv * DT };              // b-vector rows 2,5
    const f32x2 CK2 = { 0.5f, 0.5f };
    const f32x2 CK3 = { 1.0f / 6.0f, 1.0f / 6.0f };
    const f32x2 CK4 = { 1.0f / 24.0f, 1.0f / 24.0f };

    f32x2 mA = { m_init[0], m_init[3] };
    f32x2 mB = { m_init[1], m_init[4] };
    f32x2 mC = { m_init[2], m_init[5] };
    float lmax = 0.0f;

    // One Krylov matvec (d = X * s), 12 packed ops, 3 chains interleaved so
    // dependent ops sit >= 3 instructions apart (covers VALU dep latency).
#define TERMX(sA, sB, sC, dA, dB, dC, W)         \
    {                                            \
        PK_MUL_SWAP1(dA, KX2, sA);               \
        PK_MUL_SWAP1(dB, KX2, sB);               \
        PK_MUL_SWAP1(dC, KX2, sC);               \
        PK_FMA_ACC_WSLO_NEG(dA, W, sC);          \
        PK_FMA_ACC_WCHI(dB, W, sC);              \
        PK_FMA_ACC_WCHI_NEG(dC, W, sB);          \
        PK_FMA_ACC(dA, DW2, sB);                 \
        PK_FMA_ACC_NEG0(dB, DW2, sA);            \
        PK_FMA_ACC_WSLO(dC, W, sA);              \
        PK_FMA_ACC(dA, CA2, sA);                 \
        PK_FMA_ACC(dB, CA2, sB);                 \
        PK_FMA_ACC(dC, CB2, sC);                 \
    }

    // Degree-4 Taylor step of the augmented affine system (same math as the
    // scalar round-5 version, bit-identical per half).
#define BMC_STEP(W)                                                           \
    {                                                                         \
        f32x2 uA, uB, uC, vA, vB, vC;                                         \
        PK_MUL_SWAP1(uA, KX2, mA);                                            \
        PK_MUL_SWAP1(uB, KX2, mB);                                            \
        PK_FMA_SWAP1(uC, KX2, mC, BP2);                                       \
        PK_FMA_ACC_WSLO_NEG(uA, W, mC);                                       \
        PK_FMA_ACC_WCHI(uB, W, mC);                                           \
        PK_FMA_ACC_WCHI_NEG(uC, W, mB);                                       \
        PK_FMA_ACC(uA, DW2, mB);                                              \
        PK_FMA_ACC_NEG0(uB, DW2, mA);                                         \
        PK_FMA_ACC_WSLO(uC, W, mA);                                           \
        PK_FMA_ACC(uA, CA2, mA);                                              \
        PK_FMA_ACC(uB, CA2, mB);                                              \
        PK_FMA_ACC(uC, CB2, mC);                                              \
        PK_ADD_ACC(mA, uA); PK_ADD_ACC(mB, uB); PK_ADD_ACC(mC, uC);           \
        TERMX(uA, uB, uC, vA, vB, vC, W)                                      \
        PK_FMA_ACC(mA, CK2, vA); PK_FMA_ACC(mB, CK2, vB); PK_FMA_ACC(mC, CK2, vC); \
        TERMX(vA, vB, vC, uA, uB, uC, W)                                      \
        PK_FMA_ACC(mA, CK3, uA); PK_FMA_ACC(mB, CK3, uB); PK_FMA_ACC(mC, CK3, uC); \
        TERMX(uA, uB, uC, vA, vB, vC, W)                                      \
        PK_FMA_ACC(mA, CK4, vA); PK_FMA_ACC(mB, CK4, vB); PK_FMA_ACC(mC, CK4, vC); \
        lmax = fmaxf(lmax, fmaf(mA.x, mA.x, mB.x * mB.x));                    \
    }

    // 8 steps per iteration; four float4 loads prefetched one iteration ahead
    const float4* __restrict__ w4 = (const float4*)(wsc + sim * NSTEP); // 256 x float4
    float4 p0 = w4[0], p1 = w4[1], p2 = w4[2], p3 = w4[3];
    for (int j = 0; j < NSTEP / 8; ++j) {
        int jn = (j + 1) & (NSTEP / 8 - 1);          // wraps to 0 on last iter
        float4 n0 = w4[4 * jn];
        float4 n1 = w4[4 * jn + 1];
        float4 n2 = w4[4 * jn + 2];
        float4 n3 = w4[4 * jn + 3];
        { f32x2 W = { p0.x, p0.y }; BMC_STEP(W) }
        { f32x2 W = { p0.z, p0.w }; BMC_STEP(W) }
        { f32x2 W = { p1.x, p1.y }; BMC_STEP(W) }
        { f32x2 W = { p1.z, p1.w }; BMC_STEP(W) }
        { f32x2 W = { p2.x, p2.y }; BMC_STEP(W) }
        { f32x2 W = { p2.z, p2.w }; BMC_STEP(W) }
        { f32x2 W = { p3.x, p3.y }; BMC_STEP(W) }
        { f32x2 W = { p3.z, p3.w }; BMC_STEP(W) }
        p0 = n0; p1 = n1; p2 = n2; p3 = n3;
    }
#undef BMC_STEP
#undef TERMX

    // wave-64 max reduce, then one atomic per wave (sim uniform per wave)
    for (int d = 32; d >= 1; d >>= 1)
        lmax = fmaxf(lmax, __shfl_xor(lmax, d, 64));
    if ((threadIdx.x & 63) == 0)
        atomicMax(gmax + sim, __float_as_uint(lmax));   // all values >= 0

    (void)NSAMP;
}

__global__ void finalize_kernel(const unsigned int* __restrict__ gmax,
                                float* __restrict__ out) {
    int i = threadIdx.x;
    if (i < 2) out[i] = sqrtf(__uint_as_float(gmax[i]));   // float32 output
}

extern "C" void kernel_launch(void* const* d_in, const int* in_sizes, int n_in,
                              void* d_out, int out_size, void* d_ws, size_t ws_size,
                              hipStream_t stream) {
    const float* amps    = (const float*)d_in[0];   // (4,128)
    const float* phases  = (const float*)d_in[1];   // (4,128)
    const float* offsets = (const float*)d_in[2];   // (32768,)
    const float* m_init  = (const float*)d_in[3];   // (6,)
    float* out           = (float*)d_out;           // (2,) float32

    unsigned int* gmax = (unsigned int*)d_ws;                 // 2 slots
    float2* wsc = (float2*)((char*)d_ws + 256);               // 2*512 float2

    // Python-semantics accumulated phase per (sim, rf block), computed in f64
    AccPh acc;
    for (int s = 0; s < 2; ++s) {
        double rfo  = s ? -200.0 : 200.0;
        double accp = 0.0;
        for (int r = 0; r < NRF; ++r) {
            acc.a[s * 4 + r] = (float)accp;
            double pd = fmod(3.9e-05 * 128.0 * 360.0 * rfo, 360.0);
            if (pd < 0.0) pd += 360.0;      // Python % semantics
            accp += pd / 180.0 * M_PI;
        }
    }

    init_kernel<<<1, 64, 0, stream>>>(gmax);
    precomp_kernel<<<4, 256, 0, stream>>>(amps, phases, acc, wsc);
    bmc_kernel<<<(2 * NOFF) / 256, 256, 0, stream>>>(offsets, m_init, wsc, gmax);
    finalize_kernel<<<1, 64, 0, stream>>>(gmax, out);
}